// Round 1
// baseline (115.705 us; speedup 1.0000x reference)
//
#include <hip/hip_runtime.h>
#include <math.h>

// Problem constants (from reference): h [B,T,D] fp32, k scalar fp32.
#define BB 8
#define TT 2048
#define DD 512
#define LL 32            // chunk length along T
#define CC (TT / LL)     // 64 chunks
#define D4 (DD / 4)      // 128 float4 lanes = block size

__device__ __forceinline__ float get_s(const float* kp) {
    float k = *kp;
    // softplus(k) = log(1+e^k); stable for large k
    return (k > 20.0f) ? k : log1pf(expf(k));
}

// Kernel 1: per (b, chunk): chunk sum and locally-decayed chunk end
//   csum[b][c][d] = sum_{i<L} h[b, c*L+i, d]
//   cend[b][c][d] = sum_{i<L} a^(L-1-i) h[b, c*L+i, d]
__global__ __launch_bounds__(D4) void k_chunk(
    const float* __restrict__ h, const float* __restrict__ kp,
    float* __restrict__ csum, float* __restrict__ cend)
{
    const int blk = blockIdx.x;
    const int b = blk / CC, c = blk % CC;
    const int tid = threadIdx.x;
    const float s = get_s(kp);
    const float a = expf(-s);

    const float4* hp = reinterpret_cast<const float4*>(h)
                     + (size_t)(b * TT + c * LL) * D4 + tid;

    float sx = 0.f, sy = 0.f, sz = 0.f, sw = 0.f;
    float ex = 0.f, ey = 0.f, ez = 0.f, ew = 0.f;
    #pragma unroll 8
    for (int i = 0; i < LL; i++) {
        float4 x = hp[(size_t)i * D4];
        sx += x.x; sy += x.y; sz += x.z; sw += x.w;
        ex = fmaf(a, ex, x.x);
        ey = fmaf(a, ey, x.y);
        ez = fmaf(a, ez, x.z);
        ew = fmaf(a, ew, x.w);
    }
    const size_t w = (size_t)(b * CC + c) * D4 + tid;
    reinterpret_cast<float4*>(csum)[w] = make_float4(sx, sy, sz, sw);
    reinterpret_cast<float4*>(cend)[w] = make_float4(ex, ey, ez, ew);
}

// Kernel 2: per (b, chunk): reconstruct carries from chunk stats, then
// phase A: cumsum scan + per-t ||delta||^2 wave reduction into LDS,
// phase B: ctx recurrence + write |mag * ctx|.
__global__ __launch_bounds__(D4) void k_final(
    const float* __restrict__ h, const float* __restrict__ kp,
    const float* __restrict__ csum, const float* __restrict__ cend,
    float* __restrict__ out)
{
    const int blk = blockIdx.x;
    const int b = blk / CC, c = blk % CC;
    const int tid = threadIdx.x;
    const int wave = tid >> 6, lane = tid & 63;
    const float s  = get_s(kp);
    const float a  = expf(-s);
    const float aL = expf(-s * (float)LL);   // a^L (exact carry weight)

    // ---- carries: cumsum offset = sum of earlier chunk sums;
    //      ctx carry = true ctx state entering this chunk:
    //      sum_{cp<c} aL^(c-1-cp) * cend[cp]
    float cox = 0.f, coy = 0.f, coz = 0.f, cow = 0.f;
    float ccx = 0.f, ccy = 0.f, ccz = 0.f, ccw = 0.f;
    const float4* cs4 = reinterpret_cast<const float4*>(csum) + (size_t)b * CC * D4 + tid;
    const float4* ce4 = reinterpret_cast<const float4*>(cend) + (size_t)b * CC * D4 + tid;
    for (int cp = 0; cp < c; cp++) {
        float4 sv = cs4[(size_t)cp * D4];
        float4 ev = ce4[(size_t)cp * D4];
        cox += sv.x; coy += sv.y; coz += sv.z; cow += sv.w;
        ccx = fmaf(aL, ccx, ev.x);
        ccy = fmaf(aL, ccy, ev.y);
        ccz = fmaf(aL, ccz, ev.z);
        ccw = fmaf(aL, ccw, ev.w);
    }

    const int t0 = c * LL;
    const float4* hp = reinterpret_cast<const float4*>(h)
                     + (size_t)(b * TT + t0) * D4 + tid;

    // previous raw h element (t0-1), zero at t0==0
    float px = 0.f, py = 0.f, pz = 0.f, pw = 0.f;
    if (t0 > 0) {
        float4 pv = hp[-(size_t)D4];
        px = pv.x; py = pv.y; pz = pv.z; pw = pv.w;
    }

    __shared__ float m2s[2][LL];
    __shared__ float mags[LL];

    // ---- phase A: cumsum + delta^2 partials (mag does not feed the scan,
    // so no per-step barrier; wave-level shuffle reduce, lane0 -> LDS)
    #pragma unroll 4
    for (int i = 0; i < LL; i++) {
        float4 x = hp[(size_t)i * D4];
        cox += x.x; coy += x.y; coz += x.z; cow += x.w;
        float dx = cox - px, dy = coy - py, dz = coz - pz, dw = cow - pw;
        float r = dx * dx + dy * dy + dz * dz + dw * dw;
        px = x.x; py = x.y; pz = x.z; pw = x.w;
        #pragma unroll
        for (int m = 32; m > 0; m >>= 1) r += __shfl_xor(r, m, 64);
        if (lane == 0) m2s[wave][i] = r;
    }
    __syncthreads();
    if (tid < LL) mags[tid] = sqrtf(m2s[0][tid] + m2s[1][tid]);
    __syncthreads();

    // ---- phase B: ctx recurrence (h re-read is LLC-warm) + output
    float4* op = reinterpret_cast<float4*>(out)
               + (size_t)(b * TT + t0) * D4 + tid;
    #pragma unroll 4
    for (int i = 0; i < LL; i++) {
        float4 x = hp[(size_t)i * D4];
        ccx = fmaf(a, ccx, x.x);
        ccy = fmaf(a, ccy, x.y);
        ccz = fmaf(a, ccz, x.z);
        ccw = fmaf(a, ccw, x.w);
        float m = mags[i];
        float4 o = make_float4(fabsf(m * ccx), fabsf(m * ccy),
                               fabsf(m * ccz), fabsf(m * ccw));
        op[(size_t)i * D4] = o;
    }
}

extern "C" void kernel_launch(void* const* d_in, const int* in_sizes, int n_in,
                              void* d_out, int out_size, void* d_ws, size_t ws_size,
                              hipStream_t stream) {
    const float* h  = (const float*)d_in[0];
    const float* kp = (const float*)d_in[1];
    float* out  = (float*)d_out;
    float* csum = (float*)d_ws;                       // [B][C][D] = 1 MB
    float* cend = csum + (size_t)BB * CC * DD;        // [B][C][D] = 1 MB

    k_chunk<<<dim3(BB * CC), dim3(D4), 0, stream>>>(h, kp, csum, cend);
    k_final<<<dim3(BB * CC), dim3(D4), 0, stream>>>(h, kp, csum, cend, out);
}

// Round 2
// 106.212 us; speedup vs baseline: 1.0894x; 1.0894x over previous
//
#include <hip/hip_runtime.h>
#include <math.h>

// Problem constants: h [B,T,D] fp32, k scalar fp32.
#define BB 8
#define TT 2048
#define DD 512
#define LL 16            // chunk length along T (16 float4/lane -> registers)
#define CC (TT / LL)     // 128 chunks
#define D4 (DD / 4)      // 128 float4 lanes = block size

__device__ __forceinline__ float get_s(const float* kp) {
    float k = *kp;
    return (k > 20.0f) ? k : log1pf(expf(k));   // softplus, stable
}

// ---------------------------------------------------------------------------
// Kernel 1: per (b,c): chunk sum + locally-decayed chunk end.
//   csum[b][c][d] = sum_{i<L} h[b, c*L+i, d]
//   cend[b][c][d] = sum_{i<L} a^(L-1-i) h[b, c*L+i, d]
// ---------------------------------------------------------------------------
__global__ __launch_bounds__(D4) void k1_chunk(
    const float* __restrict__ h, const float* __restrict__ kp,
    float* __restrict__ csum, float* __restrict__ cend)
{
    const int blk = blockIdx.x;
    const int b = blk / CC, c = blk % CC;
    const int tid = threadIdx.x;
    const float a = expf(-get_s(kp));

    const float4* hp = reinterpret_cast<const float4*>(h)
                     + (size_t)(b * TT + c * LL) * D4 + tid;

    float4 x[LL];
    #pragma unroll
    for (int i = 0; i < LL; i++) x[i] = hp[(size_t)i * D4];

    float sx = 0.f, sy = 0.f, sz = 0.f, sw = 0.f;
    float ex = 0.f, ey = 0.f, ez = 0.f, ew = 0.f;
    #pragma unroll
    for (int i = 0; i < LL; i++) {
        sx += x[i].x; sy += x[i].y; sz += x[i].z; sw += x[i].w;
        ex = fmaf(a, ex, x[i].x);
        ey = fmaf(a, ey, x[i].y);
        ez = fmaf(a, ez, x[i].z);
        ew = fmaf(a, ew, x[i].w);
    }
    const size_t w = (size_t)(b * CC + c) * D4 + tid;
    reinterpret_cast<float4*>(csum)[w] = make_float4(sx, sy, sz, sw);
    reinterpret_cast<float4*>(cend)[w] = make_float4(ex, ey, ez, ew);
}

// ---------------------------------------------------------------------------
// Kernel 2: exclusive scan over chunks, per (b,d) float column.
//   coff[b][c][d] = sum_{cp<c} csum[b][cp][d]
//   ccar[b][c][d] = sum_{cp<c} aL^(c-1-cp) * cend[b][cp][d]   (aL = a^L)
// grid = B*D/64 = 64 blocks x 64 threads; lanes cover consecutive d.
// ---------------------------------------------------------------------------
__global__ __launch_bounds__(64) void k2_scan(
    const float* __restrict__ csum, const float* __restrict__ cend,
    const float* __restrict__ kp,
    float* __restrict__ coff, float* __restrict__ ccar)
{
    const int g = blockIdx.x * 64 + threadIdx.x;   // 0 .. B*D-1
    const int b = g >> 9;          // /512
    const int d = g & (DD - 1);    // %512
    const float s  = get_s(kp);
    const float aL = expf(-s * (float)LL);

    const size_t base = (size_t)b * CC * DD + d;
    float co = 0.f, cc = 0.f;
    #pragma unroll 8
    for (int c = 0; c < CC; c++) {
        const size_t idx = base + (size_t)c * DD;
        float sv = csum[idx];
        float ev = cend[idx];
        coff[idx] = co;
        ccar[idx] = cc;
        co += sv;
        cc = fmaf(aL, cc, ev);
    }
}

// ---------------------------------------------------------------------------
// Kernel 3: per (b,c): O(1) carry load, h chunk held in registers.
// Phase A: cumsum + ||delta||^2 shuffle-reduce -> mags in LDS.
// Phase B: ctx recurrence from registers, write |mag*ctx|.
// ---------------------------------------------------------------------------
__global__ __launch_bounds__(D4) void k3_out(
    const float* __restrict__ h, const float* __restrict__ kp,
    const float* __restrict__ coff, const float* __restrict__ ccar,
    float* __restrict__ out)
{
    const int blk = blockIdx.x;
    const int b = blk / CC, c = blk % CC;
    const int tid = threadIdx.x;
    const int wave = tid >> 6, lane = tid & 63;
    const float a = expf(-get_s(kp));

    const int t0 = c * LL;
    const float4* hp = reinterpret_cast<const float4*>(h)
                     + (size_t)(b * TT + t0) * D4 + tid;

    float4 x[LL];
    #pragma unroll
    for (int i = 0; i < LL; i++) x[i] = hp[(size_t)i * D4];

    const size_t ci = (size_t)(b * CC + c) * D4 + tid;
    float4 co = reinterpret_cast<const float4*>(coff)[ci];
    float4 cc = reinterpret_cast<const float4*>(ccar)[ci];

    float px = 0.f, py = 0.f, pz = 0.f, pw = 0.f;
    if (t0 > 0) {
        float4 pv = hp[-(size_t)D4];
        px = pv.x; py = pv.y; pz = pv.z; pw = pv.w;
    }

    __shared__ float m2s[2][LL];
    __shared__ float mags[LL];

    float cox = co.x, coy = co.y, coz = co.z, cow = co.w;
    #pragma unroll
    for (int i = 0; i < LL; i++) {
        cox += x[i].x; coy += x[i].y; coz += x[i].z; cow += x[i].w;
        float dx = cox - px, dy = coy - py, dz = coz - pz, dw = cow - pw;
        float r = dx * dx + dy * dy + dz * dz + dw * dw;
        px = x[i].x; py = x[i].y; pz = x[i].z; pw = x[i].w;
        #pragma unroll
        for (int m = 32; m > 0; m >>= 1) r += __shfl_xor(r, m, 64);
        if (lane == 0) m2s[wave][i] = r;
    }
    __syncthreads();
    if (tid < LL) mags[tid] = sqrtf(m2s[0][tid] + m2s[1][tid]);
    __syncthreads();

    float4* op = reinterpret_cast<float4*>(out)
               + (size_t)(b * TT + t0) * D4 + tid;
    float ccx = cc.x, ccy = cc.y, ccz = cc.z, ccw = cc.w;
    #pragma unroll
    for (int i = 0; i < LL; i++) {
        ccx = fmaf(a, ccx, x[i].x);
        ccy = fmaf(a, ccy, x[i].y);
        ccz = fmaf(a, ccz, x[i].z);
        ccw = fmaf(a, ccw, x[i].w);
        float m = mags[i];
        op[(size_t)i * D4] = make_float4(fabsf(m * ccx), fabsf(m * ccy),
                                         fabsf(m * ccz), fabsf(m * ccw));
    }
}

extern "C" void kernel_launch(void* const* d_in, const int* in_sizes, int n_in,
                              void* d_out, int out_size, void* d_ws, size_t ws_size,
                              hipStream_t stream) {
    const float* h  = (const float*)d_in[0];
    const float* kp = (const float*)d_in[1];
    float* out = (float*)d_out;

    const size_t NS = (size_t)BB * CC * DD;   // 512K floats = 2 MB each
    float* csum = (float*)d_ws;
    float* cend = csum + NS;
    float* coff = cend + NS;
    float* ccar = coff + NS;

    k1_chunk<<<dim3(BB * CC), dim3(D4), 0, stream>>>(h, kp, csum, cend);
    k2_scan <<<dim3(BB * DD / 64), dim3(64), 0, stream>>>(csum, cend, kp, coff, ccar);
    k3_out  <<<dim3(BB * CC), dim3(D4), 0, stream>>>(h, kp, coff, ccar, out);
}